// Round 2
// baseline (170.876 us; speedup 1.0000x reference)
//
#include <hip/hip_runtime.h>

#define Cn 128
#define ICn 64
#define Nn 4096
#define Mn 1024

// ---------------------------------------------------------------------------
// K0: pre-pack weights. wpk[(c*64+ic)*2+{0,1}] = {w1[ic][c], w4[ic][c]}.
//     ucon[0..127]=u3 (W3^T wt), ucon[128]=c3 (wt.b3), ucon[129..192]=wp.
// ---------------------------------------------------------------------------
__global__ __launch_bounds__(256) void k_pre(
    const float* __restrict__ w1, const float* __restrict__ w4,
    const float* __restrict__ w3, const float* __restrict__ b3,
    const float* __restrict__ w5,
    float* __restrict__ wpk, float* __restrict__ ucon)
{
    const int tid = threadIdx.x;
    for (int e = tid; e < 8192; e += 256) {
        int c = e >> 6, ic = e & 63;
        wpk[e * 2 + 0] = w1[ic * Cn + c];
        wpk[e * 2 + 1] = w4[ic * Cn + c];
    }
    if (tid < 128) {
        float s = 0.f;
        for (int ic = 0; ic < 64; ++ic) s += w5[ic] * w3[ic * Cn + tid];
        ucon[tid] = s;
    } else if (tid == 128) {
        float s = 0.f;
        for (int ic = 0; ic < 64; ++ic) s += w5[ic] * b3[ic];
        ucon[128] = s;
    } else if (tid < 193) {
        ucon[129 + (tid - 129)] = w5[64 + (tid - 129)];
    }
}

// ---------------------------------------------------------------------------
// K1: per (row-pair r, half-width wb): a1=W1x+b1, a4=W4x+b4 over 128c x 64px,
//     t = u3.x + c3, 2x2 maxpools -> xg rows and p.
// ---------------------------------------------------------------------------
__global__ __launch_bounds__(256) void k_conv(
    const float* __restrict__ x, const float* __restrict__ b1, const float* __restrict__ b4,
    const float* __restrict__ wpk, const float* __restrict__ ucon,
    float* __restrict__ t_o, float* __restrict__ p_o, float* __restrict__ xg_o)
{
    const int tile = blockIdx.x;   // 0..63
    const int r  = tile >> 1;      // row-pair 0..31
    const int wb = tile & 1;       // half-width 0..1
    const int b  = blockIdx.y;
    const int tid = threadIdx.x;

    __shared__ float xs[128 * 64];  // [c][lp], lp = rl*32+wl   (32 KB)
    __shared__ float wt1[64 * 64];  // [cl][ic] chunk            (16 KB)
    __shared__ float wt4[64 * 64];  //                           (16 KB)

    // ---- stage x tile (coalesced float4) ----
    for (int it = 0; it < 8; ++it) {
        int f = tid + 256 * it;        // 2048 float4s
        int c = f >> 4, rem = f & 15;
        int rl = rem >> 3, wq = rem & 7;
        const float* src = x + ((size_t)(b * Cn + c)) * Nn + (2 * r + rl) * 64 + 32 * wb + 4 * wq;
        *(float4*)&xs[c * 64 + rl * 32 + 4 * wq] = *(const float4*)src;
    }

    const int q   = tid & 15;          // pixel quad, px0 = 4q
    const int px0 = 4 * q;
    const int ic0 = (tid >> 4) * 4;    // 4 output channels

    float acc1[4][4], acc4[4][4];
    #pragma unroll
    for (int i = 0; i < 4; ++i) {
        float bb1 = b1[ic0 + i], bb4 = b4[ic0 + i];
        #pragma unroll
        for (int j = 0; j < 4; ++j) { acc1[i][j] = bb1; acc4[i][j] = bb4; }
    }

    for (int ch = 0; ch < 2; ++ch) {
        __syncthreads();   // xs ready (ch=0) / prev chunk's reads done (ch=1)
        for (int it = 0; it < 16; ++it) {
            int e = tid + 256 * it;    // 4096: ic fast -> coalesced global, bank-clean LDS
            int ic = e & 63, cl = e >> 6;
            float2 wv = *(const float2*)&wpk[(((size_t)(64 * ch + cl)) * 64 + ic) * 2];
            wt1[cl * 64 + ic] = wv.x;
            wt4[cl * 64 + ic] = wv.y;
        }
        __syncthreads();
        for (int cl = 0; cl < 64; ++cl) {
            float4 xv  = *(const float4*)&xs[(64 * ch + cl) * 64 + px0];
            float4 w1v = *(const float4*)&wt1[cl * 64 + ic0];
            float4 w4v = *(const float4*)&wt4[cl * 64 + ic0];
            float xa[4] = { xv.x, xv.y, xv.z, xv.w };
            float wa1[4] = { w1v.x, w1v.y, w1v.z, w1v.w };
            float wa4[4] = { w4v.x, w4v.y, w4v.z, w4v.w };
            #pragma unroll
            for (int i = 0; i < 4; ++i)
                #pragma unroll
                for (int j = 0; j < 4; ++j) {
                    acc1[i][j] += wa1[i] * xa[j];
                    acc4[i][j] += wa4[i] * xa[j];
                }
        }
    }
    __syncthreads();   // compute done; wt1/wt4 regions free

    float* ph = wt1;   // pool buffer [2 rl][16 pw][68]  (2176 floats, fits 4096)
    const int rl  = q >> 3;
    const int pw0 = (q & 7) * 2;
    #pragma unroll
    for (int i = 0; i < 4; ++i) {
        ph[(rl * 16 + pw0    ) * 68 + ic0 + i] = fmaxf(acc1[i][0], acc1[i][1]);
        ph[(rl * 16 + pw0 + 1) * 68 + ic0 + i] = fmaxf(acc1[i][2], acc1[i][3]);
    }
    __syncthreads();

    // xg rows (pool of a1)
    for (int e = tid; e < 1024; e += 256) {
        int pw = e >> 6, ic = e & 63;
        float v = fmaxf(ph[pw * 68 + ic], ph[(16 + pw) * 68 + ic]);
        xg_o[((size_t)b * Mn + r * 32 + wb * 16 + pw) * 64 + ic] = v;
    }
    // t for the 64 pixels
    if (tid < 64) {
        float s = ucon[128];
        for (int c = 0; c < 128; ++c) s += ucon[c] * xs[c * 64 + tid];
        t_o[(size_t)b * Nn + (2 * r + (tid >> 5)) * 64 + 32 * wb + (tid & 31)] = s;
    }
    __syncthreads();

    #pragma unroll
    for (int i = 0; i < 4; ++i) {
        ph[(rl * 16 + pw0    ) * 68 + ic0 + i] = fmaxf(acc4[i][0], acc4[i][1]);
        ph[(rl * 16 + pw0 + 1) * 68 + ic0 + i] = fmaxf(acc4[i][2], acc4[i][3]);
    }
    __syncthreads();
    if (tid < 16) {
        float s = 0.f;
        for (int ic = 0; ic < 64; ++ic)
            s += ucon[129 + ic] * fmaxf(ph[tid * 68 + ic], ph[(16 + tid) * 68 + ic]);
        p_o[(size_t)b * Mn + r * 32 + wb * 16 + tid] = s;
    }
}

// ---------------------------------------------------------------------------
// K2: g[b][m][co] = sum_i xg[b][m][i] * w2[co][i]   (two co-half passes)
// ---------------------------------------------------------------------------
__global__ __launch_bounds__(256) void k_g(
    const float* __restrict__ xg, const float* __restrict__ w2, float* __restrict__ g)
{
    const int mt = blockIdx.x;     // 0..7 (128-row m tiles)
    const int b  = blockIdx.y;
    const int tid = threadIdx.x;
    __shared__ float xgs[128 * 65];   // 33,280 B
    __shared__ float w2h[64 * 65];    // 16,640 B

    for (int it = 0; it < 8; ++it) {
        int f = tid + 256 * it;        // 2048 float4s
        int ml = f >> 4, i0 = (f & 15) * 4;
        float4 v = *(const float4*)&xg[((size_t)b * Mn + mt * 128 + ml) * 64 + i0];
        xgs[ml * 65 + i0 + 0] = v.x; xgs[ml * 65 + i0 + 1] = v.y;
        xgs[ml * 65 + i0 + 2] = v.z; xgs[ml * 65 + i0 + 3] = v.w;
    }

    const int ml0  = tid & 15;
    const int coL0 = (tid >> 4) * 4;

    for (int coh = 0; coh < 2; ++coh) {
        __syncthreads();   // xgs ready / previous pass reads done
        for (int it = 0; it < 16; ++it) {
            int e = tid + 256 * it;    // 4096: i fast -> coalesced read
            int co_l = e >> 6, i = e & 63;
            w2h[i * 65 + co_l] = w2[(coh * 64 + co_l) * 64 + i];
        }
        __syncthreads();

        float acc[8][4];
        #pragma unroll
        for (int k = 0; k < 8; ++k) for (int j = 0; j < 4; ++j) acc[k][j] = 0.f;

        for (int i = 0; i < 64; ++i) {
            float xv[8];
            #pragma unroll
            for (int k = 0; k < 8; ++k) xv[k] = xgs[(ml0 + 16 * k) * 65 + i];
            float wv[4];
            #pragma unroll
            for (int j = 0; j < 4; ++j) wv[j] = w2h[i * 65 + coL0 + j];
            #pragma unroll
            for (int k = 0; k < 8; ++k)
                #pragma unroll
                for (int j = 0; j < 4; ++j) acc[k][j] += xv[k] * wv[j];
        }
        #pragma unroll
        for (int k = 0; k < 8; ++k) {
            float4 v = { acc[k][0], acc[k][1], acc[k][2], acc[k][3] };
            *(float4*)&g[((size_t)b * Mn + mt * 128 + ml0 + 16 * k) * 128 + coh * 64 + coL0] = v;
        }
    }
}

// ---------------------------------------------------------------------------
// K3: bitonic sort p[b][0..1023] ascending, with permutation
// ---------------------------------------------------------------------------
__global__ __launch_bounds__(1024) void k_sort(
    const float* __restrict__ p, float* __restrict__ ps, int* __restrict__ perm)
{
    const int b = blockIdx.x, tid = threadIdx.x;
    __shared__ float key[1024];
    __shared__ int   idx[1024];
    key[tid] = p[b * 1024 + tid]; idx[tid] = tid;
    __syncthreads();
    for (int k = 2; k <= 1024; k <<= 1)
        for (int j = k >> 1; j > 0; j >>= 1) {
            int ixj = tid ^ j;
            if (ixj > tid) {
                float a = key[tid], c2 = key[ixj];
                bool up = (tid & k) == 0;
                if (up ? (a > c2) : (a < c2)) {
                    key[tid] = c2; key[ixj] = a;
                    int tmp = idx[tid]; idx[tid] = idx[ixj]; idx[ixj] = tmp;
                }
            }
            __syncthreads();
        }
    ps[b * 1024 + tid] = key[tid];
    perm[b * 1024 + tid] = idx[tid];
}

// ---------------------------------------------------------------------------
// K4: per 32-j segment chunk sums of g_sorted and p*g_sorted
// ---------------------------------------------------------------------------
__global__ __launch_bounds__(256) void k_scanA(
    const float* __restrict__ g, const float* __restrict__ ps, const int* __restrict__ perm,
    float* __restrict__ csa, float* __restrict__ csb)
{
    const int seg = blockIdx.x;    // 0..31
    const int b = blockIdx.y;
    const int tid = threadIdx.x;
    const int co = tid & 127, jh = tid >> 7;
    __shared__ float redA[2][128], redB[2][128];
    __shared__ float pl[32];
    __shared__ int   pml[32];
    if (tid < 32) { pl[tid] = ps[b * 1024 + seg * 32 + tid]; pml[tid] = perm[b * 1024 + seg * 32 + tid]; }
    __syncthreads();
    float sA = 0.f, sB = 0.f;
    for (int jj = jh * 16; jj < jh * 16 + 16; ++jj) {
        float gv = g[((size_t)b * Mn + pml[jj]) * 128 + co];
        sA += gv; sB += pl[jj] * gv;
    }
    redA[jh][co] = sA; redB[jh][co] = sB;
    __syncthreads();
    if (tid < 128) {
        csa[(b * 32 + seg) * 128 + tid] = redA[0][tid] + redA[1][tid];
        csb[(b * 32 + seg) * 128 + tid] = redB[0][tid] + redB[1][tid];
    }
}

// ---------------------------------------------------------------------------
// K5: suffix-sum walk -> SA[b][k][co], SB[b][k][co], k in [0,1024]
// ---------------------------------------------------------------------------
__global__ __launch_bounds__(128) void k_scanC(
    const float* __restrict__ g, const float* __restrict__ ps, const int* __restrict__ perm,
    const float* __restrict__ csa, const float* __restrict__ csb,
    float* __restrict__ SA, float* __restrict__ SB)
{
    const int seg = blockIdx.x;    // 0..31
    const int b = blockIdx.y;
    const int tid = threadIdx.x;   // 128 threads = co
    __shared__ float pl[32];
    __shared__ int   pml[32];
    if (tid < 32) { pl[tid] = ps[b * 1024 + seg * 32 + tid]; pml[tid] = perm[b * 1024 + seg * 32 + tid]; }
    __syncthreads();
    const int co = tid;
    float rA = 0.f, rB = 0.f;
    for (int s = seg + 1; s < 32; ++s) {
        rA += csa[(b * 32 + s) * 128 + co];
        rB += csb[(b * 32 + s) * 128 + co];
    }
    if (seg == 31) {
        SA[((size_t)b * 1025 + 1024) * 128 + co] = 0.f;
        SB[((size_t)b * 1025 + 1024) * 128 + co] = 0.f;
    }
    for (int jj = 31; jj >= 0; --jj) {
        int j = seg * 32 + jj;
        float gv = g[((size_t)b * Mn + pml[jj]) * 128 + co];
        rA += gv; rB += pl[jj] * gv;
        SA[((size_t)b * 1025 + j) * 128 + co] = rA;
        SB[((size_t)b * 1025 + j) * 128 + co] = rB;
    }
}

// ---------------------------------------------------------------------------
// K6: out[b][co][n] = ((t[n]*SA[k(n)][co] + SB[k(n)][co])/M)*sc[co] + bs[co] + x
// ---------------------------------------------------------------------------
__global__ __launch_bounds__(256) void k_final(
    const float* __restrict__ x, const float* __restrict__ t,
    const float* __restrict__ ps, const float* __restrict__ SA, const float* __restrict__ SB,
    const float* __restrict__ b2, const float* __restrict__ gamma, const float* __restrict__ beta,
    const float* __restrict__ mean, const float* __restrict__ var,
    float* __restrict__ out)
{
    const int nt = blockIdx.x;     // 0..31 (128-pixel n tiles)
    const int b = blockIdx.y;
    const int tid = threadIdx.x;
    const int n0 = nt * 128;
    __shared__ float psl[1024];
    __shared__ float tl[128];
    __shared__ int   kl[128];
    __shared__ float sc[128], bs[128];
    __shared__ float sa_s[32][129], sb_s[32][129];

    for (int it = 0; it < 4; ++it) psl[tid + 256 * it] = ps[b * 1024 + tid + 256 * it];
    __syncthreads();
    if (tid < 128) {
        float tv = t[(size_t)b * Nn + n0 + tid];
        tl[tid] = tv;
        float key = -tv;
        int lo = 0, hi = 1024;
        while (lo < hi) { int mid = (lo + hi) >> 1; if (psl[mid] > key) hi = mid; else lo = mid + 1; }
        kl[tid] = lo;
    } else {
        int co = tid - 128;
        float s = gamma[co] * rsqrtf(var[co] + 1e-5f);
        sc[co] = s;
        bs[co] = (b2[co] - mean[co]) * s + beta[co];
    }
    __syncthreads();

    const float invM = 1.0f / 1024.0f;
    for (int sub = 0; sub < 4; ++sub) {
        for (int it = 0; it < 16; ++it) {
            int f = tid + 256 * it;          // 4096: 32 rows x 128 co
            int rowl = f >> 7, co = f & 127;
            int k = kl[sub * 32 + rowl];
            sa_s[rowl][co] = SA[((size_t)b * 1025 + k) * 128 + co];
            sb_s[rowl][co] = SB[((size_t)b * 1025 + k) * 128 + co];
        }
        __syncthreads();
        for (int it = 0; it < 4; ++it) {
            int f = tid + 256 * it;          // 1024 float4s: 128 co x 8 n-quads
            int co = f >> 3, nn0 = (f & 7) * 4;
            size_t gidx = ((size_t)b * Cn + co) * Nn + n0 + sub * 32 + nn0;
            float4 xv = *(const float4*)&x[gidx];
            float scv = sc[co], bsv = bs[co];
            float4 o;
            {
                float v0 = (tl[sub*32+nn0+0] * sa_s[nn0+0][co] + sb_s[nn0+0][co]) * invM;
                float v1 = (tl[sub*32+nn0+1] * sa_s[nn0+1][co] + sb_s[nn0+1][co]) * invM;
                float v2 = (tl[sub*32+nn0+2] * sa_s[nn0+2][co] + sb_s[nn0+2][co]) * invM;
                float v3 = (tl[sub*32+nn0+3] * sa_s[nn0+3][co] + sb_s[nn0+3][co]) * invM;
                o.x = v0 * scv + bsv + xv.x;
                o.y = v1 * scv + bsv + xv.y;
                o.z = v2 * scv + bsv + xv.z;
                o.w = v3 * scv + bsv + xv.w;
            }
            *(float4*)&out[gidx] = o;
        }
        __syncthreads();
    }
}

// ---------------------------------------------------------------------------
extern "C" void kernel_launch(void* const* d_in, const int* in_sizes, int n_in,
                              void* d_out, int out_size, void* d_ws, size_t ws_size,
                              hipStream_t stream)
{
    const float* x  = (const float*)d_in[0];
    const float* w1 = (const float*)d_in[1];
    const float* b1 = (const float*)d_in[2];
    const float* w3 = (const float*)d_in[3];
    const float* b3 = (const float*)d_in[4];
    const float* w4 = (const float*)d_in[5];
    const float* b4 = (const float*)d_in[6];
    const float* w5 = (const float*)d_in[7];
    const float* w2 = (const float*)d_in[8];
    const float* b2 = (const float*)d_in[9];
    const float* gm = (const float*)d_in[10];
    const float* bt = (const float*)d_in[11];
    const float* mn = (const float*)d_in[12];
    const float* vr = (const float*)d_in[13];
    float* out = (float*)d_out;

    float* ws = (float*)d_ws;
    const size_t FTOT = 3811584;           // floats (~15.25 MB)
    if (ws_size < FTOT * sizeof(float)) return;  // visible failure (zeros) rather than overrun

    float* t_w  = ws;                      // 32768
    float* p_w  = ws + 32768;              // 8192
    float* ps_w = ws + 40960;              // 8192
    int*   pm_w = (int*)(ws + 49152);      // 8192
    float* xg_w = ws + 57344;              // 524288
    float* g_w  = ws + 581632;             // 1048576
    float* csa  = ws + 1630208;            // 32768
    float* csb  = ws + 1662976;            // 32768
    float* SAp  = ws + 1695744;            // 1049600
    float* SBp  = ws + 2745344;            // 1049600
    float* wpk  = ws + 3794944;            // 16384
    float* ucon = ws + 3811328;            // 256

    k_pre  <<<1,           256, 0, stream>>>(w1, w4, w3, b3, w5, wpk, ucon);
    k_conv <<<dim3(64, 8), 256, 0, stream>>>(x, b1, b4, wpk, ucon, t_w, p_w, xg_w);
    k_g    <<<dim3(8, 8),  256, 0, stream>>>(xg_w, w2, g_w);
    k_sort <<<8,           1024, 0, stream>>>(p_w, ps_w, pm_w);
    k_scanA<<<dim3(32, 8), 256, 0, stream>>>(g_w, ps_w, pm_w, csa, csb);
    k_scanC<<<dim3(32, 8), 128, 0, stream>>>(g_w, ps_w, pm_w, csa, csb, SAp, SBp);
    k_final<<<dim3(32, 8), 256, 0, stream>>>(x, t_w, ps_w, SAp, SBp, b2, gm, bt, mn, vr, out);
}